// Round 1
// baseline (2572.948 us; speedup 1.0000x reference)
//
#include <hip/hip_runtime.h>
#include <cstdint>

#define N_NODES 20000
#define N_EDGES 100000
#define LEAKK 0.1f
#define BN_EPS 1e-5f

__device__ __forceinline__ float lrelu(float v) { return v > 0.f ? v : LEAKK * v; }
__device__ __forceinline__ float4 ld4(const float* p) { return *reinterpret_cast<const float4*>(p); }

__device__ __forceinline__ void atomAddF(float* p, float v) {
#if defined(__HIP_DEVICE_COMPILE__)
    unsafeAtomicAdd(p, v);   // hardware global_atomic_add_f32
#else
    atomicAdd(p, v);
#endif
}

// ---------------- column stats: sum + sumsq over rows ----------------
template<int C>
__global__ void stats_kernel(const float* __restrict__ v, int rows, float* __restrict__ out /*[2C]*/) {
    float s[C], q[C];
    #pragma unroll
    for (int c = 0; c < C; ++c) { s[c] = 0.f; q[c] = 0.f; }
    int stride = gridDim.x * blockDim.x;
    for (int r = blockIdx.x * blockDim.x + threadIdx.x; r < rows; r += stride) {
        #pragma unroll
        for (int c = 0; c < C; ++c) {
            float x = v[r * C + c];
            s[c] += x; q[c] += x * x;
        }
    }
    #pragma unroll
    for (int c = 0; c < C; ++c) {
        float a = s[c], b = q[c];
        for (int off = 32; off > 0; off >>= 1) {
            a += __shfl_down(a, off, 64);
            b += __shfl_down(b, off, 64);
        }
        if ((threadIdx.x & 63) == 0) {
            atomAddF(&out[c], a);
            atomAddF(&out[C + c], b);
        }
    }
}

// ---------------- batchnorm apply ----------------
template<int C>
__global__ void normalize_kernel(const float* __restrict__ v, int rows,
                                 const float* __restrict__ stats,
                                 const float* __restrict__ g, const float* __restrict__ b,
                                 float* __restrict__ outp) {
    int idx = blockIdx.x * blockDim.x + threadIdx.x;
    int total = rows * C;
    if (idx >= total) return;
    int c = idx % C;
    float N = (float)rows;
    float m = stats[c] / N;
    float var = stats[C + c] / N - m * m;
    float sc = rsqrtf(var + BN_EPS) * g[c];
    outp[idx] = (v[idx] - m) * sc + b[c];
}

// ---------------- root transform: xout = xin @ W + bias ----------------
template<int CIN, int COUT>
__global__ void root_kernel(const float* __restrict__ xin, int nodes,
                            const float* __restrict__ w /*[CIN,COUT]*/,
                            const float* __restrict__ bias,
                            float* __restrict__ xout) {
    int n = blockIdx.x * blockDim.x + threadIdx.x;
    if (n >= nodes) return;
    float xi[CIN];
    #pragma unroll
    for (int i = 0; i < CIN; ++i) xi[i] = xin[n * CIN + i];
    #pragma unroll 4
    for (int o = 0; o < COUT; ++o) {
        float acc = bias[o];
        #pragma unroll
        for (int i = 0; i < CIN; ++i) acc += xi[i] * w[i * COUT + o];
        xout[n * COUT + o] = acc;
    }
}

// ---------------- fused NNConv edge kernel ----------------
// per edge: h = lrelu(e_n @ w1 + b1)   [H]
//           W[i][o] = lrelu(sum_k h[k]*w2[k][i*COUT+o] + b2[i*COUT+o])
//           msg[o]  = sum_i x[src][i] * W[i][o]
//           atomicAdd(xout[dst], msg)
template<int CIN, int COUT, int H>
__global__ void conv_edge_kernel(
    const float* __restrict__ e_n,
    const int* __restrict__ src, const int* __restrict__ dst,
    const float* __restrict__ xin,
    const float* __restrict__ w1, const float* __restrict__ b1,
    const float* __restrict__ w2, const float* __restrict__ b2,
    float* __restrict__ xout, int n_edges)
{
    constexpr int EIN = 10;
    int e = blockIdx.x * blockDim.x + threadIdx.x;
    if (e >= n_edges) return;
    int s = src[e], d = dst[e];

    float ev[EIN];
    #pragma unroll
    for (int j = 0; j < EIN; ++j) ev[j] = e_n[e * EIN + j];

    float h[H];
    #pragma unroll
    for (int k = 0; k < H; ++k) {
        float acc = b1[k];
        #pragma unroll
        for (int j = 0; j < EIN; ++j) acc += ev[j] * w1[j * H + k];
        h[k] = lrelu(acc);
    }

    float4 msg[COUT / 4];
    #pragma unroll
    for (int o = 0; o < COUT / 4; ++o) msg[o] = make_float4(0.f, 0.f, 0.f, 0.f);

    const float* xrow = xin + (size_t)s * CIN;
    #pragma unroll 1
    for (int i = 0; i < CIN; ++i) {
        float xi = xrow[i];
        const float* b2p = b2 + i * COUT;
        const float* w2p = w2 + i * COUT;
        #pragma unroll
        for (int o = 0; o < COUT / 4; ++o) {
            float4 wa = ld4(b2p + o * 4);
            #pragma unroll
            for (int k = 0; k < H; ++k) {
                float4 w = ld4(w2p + (size_t)k * (CIN * COUT) + o * 4);
                wa.x += h[k] * w.x; wa.y += h[k] * w.y;
                wa.z += h[k] * w.z; wa.w += h[k] * w.w;
            }
            msg[o].x += xi * lrelu(wa.x);
            msg[o].y += xi * lrelu(wa.y);
            msg[o].z += xi * lrelu(wa.z);
            msg[o].w += xi * lrelu(wa.w);
        }
    }

    float* orow = xout + (size_t)d * COUT;
    #pragma unroll
    for (int o = 0; o < COUT / 4; ++o) {
        atomAddF(orow + o * 4 + 0, msg[o].x);
        atomAddF(orow + o * 4 + 1, msg[o].y);
        atomAddF(orow + o * 4 + 2, msg[o].z);
        atomAddF(orow + o * 4 + 3, msg[o].w);
    }
}

// ---------------- edge-prediction MLP: 138 -> 64 -> 32 -> 16 -> 8 -> 2 ----------------
__global__ void mlp_kernel(const float* __restrict__ x2, const float* __restrict__ e_n,
                           const int* __restrict__ src, const int* __restrict__ dst,
                           const float* __restrict__ w1, const float* __restrict__ b1,
                           const float* __restrict__ w2, const float* __restrict__ b2,
                           const float* __restrict__ w3, const float* __restrict__ b3,
                           const float* __restrict__ w4, const float* __restrict__ b4,
                           const float* __restrict__ w5, const float* __restrict__ b5,
                           float* __restrict__ out, int n_edges)
{
    int e = blockIdx.x * blockDim.x + threadIdx.x;
    if (e >= n_edges) return;
    int s = src[e], d = dst[e];

    float a1[64];
    #pragma unroll
    for (int j = 0; j < 64; ++j) a1[j] = b1[j];

    const float* xs = x2 + (size_t)s * 64;
    const float* xd = x2 + (size_t)d * 64;
    #pragma unroll 1
    for (int i = 0; i < 64; ++i) {
        float xi = xs[i];
        const float* wr = w1 + i * 64;
        #pragma unroll
        for (int j = 0; j < 64; ++j) a1[j] += xi * wr[j];
    }
    #pragma unroll 1
    for (int i = 0; i < 64; ++i) {
        float xi = xd[i];
        const float* wr = w1 + (64 + i) * 64;
        #pragma unroll
        for (int j = 0; j < 64; ++j) a1[j] += xi * wr[j];
    }
    #pragma unroll 1
    for (int i = 0; i < 10; ++i) {
        float xi = e_n[(size_t)e * 10 + i];
        const float* wr = w1 + (128 + i) * 64;
        #pragma unroll
        for (int j = 0; j < 64; ++j) a1[j] += xi * wr[j];
    }
    #pragma unroll
    for (int j = 0; j < 64; ++j) a1[j] = lrelu(a1[j]);

    float a2[32];
    #pragma unroll
    for (int j = 0; j < 32; ++j) a2[j] = b2[j];
    #pragma unroll
    for (int i = 0; i < 64; ++i) {
        #pragma unroll
        for (int j = 0; j < 32; ++j) a2[j] += a1[i] * w2[i * 32 + j];
    }
    #pragma unroll
    for (int j = 0; j < 32; ++j) a2[j] = lrelu(a2[j]);

    float a3[16];
    #pragma unroll
    for (int j = 0; j < 16; ++j) a3[j] = b3[j];
    #pragma unroll
    for (int i = 0; i < 32; ++i) {
        #pragma unroll
        for (int j = 0; j < 16; ++j) a3[j] += a2[i] * w3[i * 16 + j];
    }
    #pragma unroll
    for (int j = 0; j < 16; ++j) a3[j] = lrelu(a3[j]);

    float a4[8];
    #pragma unroll
    for (int j = 0; j < 8; ++j) a4[j] = b4[j];
    #pragma unroll
    for (int i = 0; i < 16; ++i) {
        #pragma unroll
        for (int j = 0; j < 8; ++j) a4[j] += a3[i] * w4[i * 8 + j];
    }
    #pragma unroll
    for (int j = 0; j < 8; ++j) a4[j] = lrelu(a4[j]);

    float a5[2];
    #pragma unroll
    for (int j = 0; j < 2; ++j) a5[j] = b5[j];
    #pragma unroll
    for (int i = 0; i < 8; ++i) {
        #pragma unroll
        for (int j = 0; j < 2; ++j) a5[j] += a4[i] * w5[i * 2 + j];
    }
    out[(size_t)e * 2 + 0] = a5[0];
    out[(size_t)e * 2 + 1] = a5[1];
}

// ---------------- launch ----------------
extern "C" void kernel_launch(void* const* d_in, const int* in_sizes, int n_in,
                              void* d_out, int out_size, void* d_ws, size_t ws_size,
                              hipStream_t stream)
{
    const float* x  = (const float*)d_in[0];
    const float* e  = (const float*)d_in[1];
    const int*   ei = (const int*)d_in[2];
    // d_in[3] = xbatch (unused)
    const float* bn_node_g = (const float*)d_in[4];
    const float* bn_node_b = (const float*)d_in[5];
    const float* bn_edge_g = (const float*)d_in[6];
    const float* bn_edge_b = (const float*)d_in[7];
    const float* nn1_w1 = (const float*)d_in[8];
    const float* nn1_b1 = (const float*)d_in[9];
    const float* nn1_w2 = (const float*)d_in[10];
    const float* nn1_b2 = (const float*)d_in[11];
    const float* nn2_w1 = (const float*)d_in[12];
    const float* nn2_b1 = (const float*)d_in[13];
    const float* nn2_w2 = (const float*)d_in[14];
    const float* nn2_b2 = (const float*)d_in[15];
    const float* l1_root = (const float*)d_in[16];
    const float* l1_bias = (const float*)d_in[17];
    const float* l2_root = (const float*)d_in[18];
    const float* l2_bias = (const float*)d_in[19];
    const float* mw1 = (const float*)d_in[20]; const float* mb1 = (const float*)d_in[21];
    const float* mw2 = (const float*)d_in[22]; const float* mb2 = (const float*)d_in[23];
    const float* mw3 = (const float*)d_in[24]; const float* mb3 = (const float*)d_in[25];
    const float* mw4 = (const float*)d_in[26]; const float* mb4 = (const float*)d_in[27];
    const float* mw5 = (const float*)d_in[28]; const float* mb5 = (const float*)d_in[29];

    const int* src = ei;
    const int* dst = ei + N_EDGES;

    float* ws = (float*)d_ws;
    float* stats_e = ws;            // 20 floats
    float* stats_x = ws + 32;       // 32 floats
    float* e_n = ws + 64;                       // 100000*10 = 1,000,000
    float* x_n = ws + 64 + 1000000;             // 20000*16  =   320,000
    float* x1  = ws + 64 + 1000000 + 320000;    // 20000*32  =   640,000
    float* x2  = ws + 64 + 1000000 + 320000 + 640000;  // 20000*64 = 1,280,000
    float* out = (float*)d_out;

    // zero the stats accumulators (ws is poisoned with 0xAA before every call)
    hipMemsetAsync(d_ws, 0, 256, stream);

    stats_kernel<10><<<200, 256, 0, stream>>>(e, N_EDGES, stats_e);
    stats_kernel<16><<<100, 256, 0, stream>>>(x, N_NODES, stats_x);

    normalize_kernel<10><<<(N_EDGES * 10 + 255) / 256, 256, 0, stream>>>(
        e, N_EDGES, stats_e, bn_edge_g, bn_edge_b, e_n);
    normalize_kernel<16><<<(N_NODES * 16 + 255) / 256, 256, 0, stream>>>(
        x, N_NODES, stats_x, bn_node_g, bn_node_b, x_n);

    // layer 1: x1 = x_n @ l1_root + l1_bias, then scatter-add messages
    root_kernel<16, 32><<<(N_NODES + 255) / 256, 256, 0, stream>>>(x_n, N_NODES, l1_root, l1_bias, x1);
    conv_edge_kernel<16, 32, 16><<<(N_EDGES + 255) / 256, 256, 0, stream>>>(
        e_n, src, dst, x_n, nn1_w1, nn1_b1, nn1_w2, nn1_b2, x1, N_EDGES);

    // layer 2
    root_kernel<32, 64><<<(N_NODES + 255) / 256, 256, 0, stream>>>(x1, N_NODES, l2_root, l2_bias, x2);
    conv_edge_kernel<32, 64, 32><<<(N_EDGES + 255) / 256, 256, 0, stream>>>(
        e_n, src, dst, x1, nn2_w1, nn2_b1, nn2_w2, nn2_b2, x2, N_EDGES);

    // edge MLP
    mlp_kernel<<<(N_EDGES + 255) / 256, 256, 0, stream>>>(
        x2, e_n, src, dst, mw1, mb1, mw2, mb2, mw3, mb3, mw4, mb4, mw5, mb5, out, N_EDGES);
}

// Round 2
// 1139.914 us; speedup vs baseline: 2.2571x; 2.2571x over previous
//
#include <hip/hip_runtime.h>
#include <cstdint>

#define N_NODES 20000
#define N_EDGES 100000
#define LEAKK 0.1f
#define BN_EPS 1e-5f

__device__ __forceinline__ float lrelu(float v) { return v > 0.f ? v : LEAKK * v; }
__device__ __forceinline__ float4 ld4(const float* p) { return *reinterpret_cast<const float4*>(p); }

__device__ __forceinline__ void atomAddF(float* p, float v) {
#if defined(__HIP_DEVICE_COMPILE__)
    unsafeAtomicAdd(p, v);   // hardware global_atomic_add_f32
#else
    atomicAdd(p, v);
#endif
}

// ---------------- column stats: sum + sumsq over rows ----------------
template<int C>
__global__ void stats_kernel(const float* __restrict__ v, int rows, float* __restrict__ out /*[2C]*/) {
    float s[C], q[C];
    #pragma unroll
    for (int c = 0; c < C; ++c) { s[c] = 0.f; q[c] = 0.f; }
    int stride = gridDim.x * blockDim.x;
    for (int r = blockIdx.x * blockDim.x + threadIdx.x; r < rows; r += stride) {
        #pragma unroll
        for (int c = 0; c < C; ++c) {
            float x = v[r * C + c];
            s[c] += x; q[c] += x * x;
        }
    }
    #pragma unroll
    for (int c = 0; c < C; ++c) {
        float a = s[c], b = q[c];
        for (int off = 32; off > 0; off >>= 1) {
            a += __shfl_down(a, off, 64);
            b += __shfl_down(b, off, 64);
        }
        if ((threadIdx.x & 63) == 0) {
            atomAddF(&out[c], a);
            atomAddF(&out[C + c], b);
        }
    }
}

// ---------------- batchnorm apply ----------------
template<int C>
__global__ void normalize_kernel(const float* __restrict__ v, int rows,
                                 const float* __restrict__ stats,
                                 const float* __restrict__ g, const float* __restrict__ b,
                                 float* __restrict__ outp) {
    int idx = blockIdx.x * blockDim.x + threadIdx.x;
    int total = rows * C;
    if (idx >= total) return;
    int c = idx % C;
    float N = (float)rows;
    float m = stats[c] / N;
    float var = stats[C + c] / N - m * m;
    float sc = rsqrtf(var + BN_EPS) * g[c];
    outp[idx] = (v[idx] - m) * sc + b[c];
}

// ---------------- root transform: xout = xin @ W + bias ----------------
template<int CIN, int COUT>
__global__ void root_kernel(const float* __restrict__ xin, int nodes,
                            const float* __restrict__ w /*[CIN,COUT]*/,
                            const float* __restrict__ bias,
                            float* __restrict__ xout) {
    int n = blockIdx.x * blockDim.x + threadIdx.x;
    if (n >= nodes) return;
    float xi[CIN];
    #pragma unroll
    for (int i = 0; i < CIN; ++i) xi[i] = xin[n * CIN + i];
    #pragma unroll 4
    for (int o = 0; o < COUT; ++o) {
        float acc = bias[o];
        #pragma unroll
        for (int i = 0; i < CIN; ++i) acc += xi[i] * w[i * COUT + o];
        xout[n * COUT + o] = acc;
    }
}

// ---------------- fused NNConv edge kernel ----------------
// per edge: h = lrelu(e_n @ w1 + b1)   [H]
//           W[i][o] = lrelu(sum_k h[k]*w2[k][i*COUT+o] + b2[i*COUT+o])
//           msg[o]  = sum_i x[src][i] * W[i][o]
//           atomicAdd(xout[dst], msg)
//
// o-loop is OUTERMOST in chunks of OC so the live set is h[H]+xr[CIN]+msg[OC]+wa[OC]
// (fits in 128 VGPRs — round-1 version kept msg[64] live and spilled 519 MB to scratch).
// All w1/b1/w2/b2 accesses are wave-uniform -> compiler scalarizes to s_load.
template<int CIN, int COUT, int H, int OC>
__global__ __launch_bounds__(256, 4)
void conv_edge_kernel(
    const float* __restrict__ e_n,
    const int* __restrict__ src, const int* __restrict__ dst,
    const float* __restrict__ xin,
    const float* __restrict__ w1, const float* __restrict__ b1,
    const float* __restrict__ w2, const float* __restrict__ b2,
    float* __restrict__ xout, int n_edges)
{
    constexpr int EIN = 10;
    int e = blockIdx.x * blockDim.x + threadIdx.x;
    if (e >= n_edges) return;
    int s = src[e], d = dst[e];

    float ev[EIN];
    #pragma unroll
    for (int j = 0; j < EIN; ++j) ev[j] = e_n[(size_t)e * EIN + j];

    float h[H];
    #pragma unroll
    for (int k = 0; k < H; ++k) {
        float acc = b1[k];
        #pragma unroll
        for (int j = 0; j < EIN; ++j) acc += ev[j] * w1[j * H + k];
        h[k] = lrelu(acc);
    }

    float xr[CIN];
    const float* xrow = xin + (size_t)s * CIN;
    #pragma unroll
    for (int i = 0; i < CIN; ++i) xr[i] = xrow[i];

    float* orow = xout + (size_t)d * COUT;

    #pragma unroll 1
    for (int ob = 0; ob < COUT; ob += OC) {
        float msg[OC];
        #pragma unroll
        for (int t = 0; t < OC; ++t) msg[t] = 0.f;

        #pragma unroll 1
        for (int i = 0; i < CIN; ++i) {
            float wa[OC];
            const float* b2p = b2 + i * COUT + ob;
            #pragma unroll
            for (int t = 0; t < OC; t += 4) {
                float4 bb = ld4(b2p + t);
                wa[t] = bb.x; wa[t + 1] = bb.y; wa[t + 2] = bb.z; wa[t + 3] = bb.w;
            }
            const float* w2p = w2 + i * COUT + ob;
            #pragma unroll
            for (int k = 0; k < H; ++k) {
                float hk = h[k];
                #pragma unroll
                for (int t = 0; t < OC; t += 4) {
                    float4 w = ld4(w2p + (size_t)k * (CIN * COUT) + t);
                    wa[t]     += hk * w.x;
                    wa[t + 1] += hk * w.y;
                    wa[t + 2] += hk * w.z;
                    wa[t + 3] += hk * w.w;
                }
            }
            float xi = xr[i];
            #pragma unroll
            for (int t = 0; t < OC; ++t) msg[t] += xi * lrelu(wa[t]);
        }

        #pragma unroll
        for (int t = 0; t < OC; ++t) atomAddF(orow + ob + t, msg[t]);
    }
}

// ---------------- edge-prediction MLP: 138 -> 64 -> 32 -> 16 -> 8 -> 2 ----------------
__global__ __launch_bounds__(256, 2)
void mlp_kernel(const float* __restrict__ x2, const float* __restrict__ e_n,
                const int* __restrict__ src, const int* __restrict__ dst,
                const float* __restrict__ w1, const float* __restrict__ b1,
                const float* __restrict__ w2, const float* __restrict__ b2,
                const float* __restrict__ w3, const float* __restrict__ b3,
                const float* __restrict__ w4, const float* __restrict__ b4,
                const float* __restrict__ w5, const float* __restrict__ b5,
                float* __restrict__ out, int n_edges)
{
    int e = blockIdx.x * blockDim.x + threadIdx.x;
    if (e >= n_edges) return;
    int s = src[e], d = dst[e];

    float a1[64];
    #pragma unroll
    for (int j = 0; j < 64; ++j) a1[j] = b1[j];

    const float* xs = x2 + (size_t)s * 64;
    const float* xd = x2 + (size_t)d * 64;
    #pragma unroll 1
    for (int i = 0; i < 64; ++i) {
        float xi = xs[i];
        const float* wr = w1 + i * 64;
        #pragma unroll
        for (int j = 0; j < 64; ++j) a1[j] += xi * wr[j];
    }
    #pragma unroll 1
    for (int i = 0; i < 64; ++i) {
        float xi = xd[i];
        const float* wr = w1 + (64 + i) * 64;
        #pragma unroll
        for (int j = 0; j < 64; ++j) a1[j] += xi * wr[j];
    }
    #pragma unroll 1
    for (int i = 0; i < 10; ++i) {
        float xi = e_n[(size_t)e * 10 + i];
        const float* wr = w1 + (128 + i) * 64;
        #pragma unroll
        for (int j = 0; j < 64; ++j) a1[j] += xi * wr[j];
    }
    #pragma unroll
    for (int j = 0; j < 64; ++j) a1[j] = lrelu(a1[j]);

    float a2[32];
    #pragma unroll
    for (int j = 0; j < 32; ++j) a2[j] = b2[j];
    #pragma unroll
    for (int i = 0; i < 64; ++i) {
        #pragma unroll
        for (int j = 0; j < 32; ++j) a2[j] += a1[i] * w2[i * 32 + j];
    }
    #pragma unroll
    for (int j = 0; j < 32; ++j) a2[j] = lrelu(a2[j]);

    float a3[16];
    #pragma unroll
    for (int j = 0; j < 16; ++j) a3[j] = b3[j];
    #pragma unroll
    for (int i = 0; i < 32; ++i) {
        #pragma unroll
        for (int j = 0; j < 16; ++j) a3[j] += a2[i] * w3[i * 16 + j];
    }
    #pragma unroll
    for (int j = 0; j < 16; ++j) a3[j] = lrelu(a3[j]);

    float a4[8];
    #pragma unroll
    for (int j = 0; j < 8; ++j) a4[j] = b4[j];
    #pragma unroll
    for (int i = 0; i < 16; ++i) {
        #pragma unroll
        for (int j = 0; j < 8; ++j) a4[j] += a3[i] * w4[i * 8 + j];
    }
    #pragma unroll
    for (int j = 0; j < 8; ++j) a4[j] = lrelu(a4[j]);

    float a5[2];
    #pragma unroll
    for (int j = 0; j < 2; ++j) a5[j] = b5[j];
    #pragma unroll
    for (int i = 0; i < 8; ++i) {
        #pragma unroll
        for (int j = 0; j < 2; ++j) a5[j] += a4[i] * w5[i * 2 + j];
    }
    out[(size_t)e * 2 + 0] = a5[0];
    out[(size_t)e * 2 + 1] = a5[1];
}

// ---------------- launch ----------------
extern "C" void kernel_launch(void* const* d_in, const int* in_sizes, int n_in,
                              void* d_out, int out_size, void* d_ws, size_t ws_size,
                              hipStream_t stream)
{
    const float* x  = (const float*)d_in[0];
    const float* e  = (const float*)d_in[1];
    const int*   ei = (const int*)d_in[2];
    // d_in[3] = xbatch (unused)
    const float* bn_node_g = (const float*)d_in[4];
    const float* bn_node_b = (const float*)d_in[5];
    const float* bn_edge_g = (const float*)d_in[6];
    const float* bn_edge_b = (const float*)d_in[7];
    const float* nn1_w1 = (const float*)d_in[8];
    const float* nn1_b1 = (const float*)d_in[9];
    const float* nn1_w2 = (const float*)d_in[10];
    const float* nn1_b2 = (const float*)d_in[11];
    const float* nn2_w1 = (const float*)d_in[12];
    const float* nn2_b1 = (const float*)d_in[13];
    const float* nn2_w2 = (const float*)d_in[14];
    const float* nn2_b2 = (const float*)d_in[15];
    const float* l1_root = (const float*)d_in[16];
    const float* l1_bias = (const float*)d_in[17];
    const float* l2_root = (const float*)d_in[18];
    const float* l2_bias = (const float*)d_in[19];
    const float* mw1 = (const float*)d_in[20]; const float* mb1 = (const float*)d_in[21];
    const float* mw2 = (const float*)d_in[22]; const float* mb2 = (const float*)d_in[23];
    const float* mw3 = (const float*)d_in[24]; const float* mb3 = (const float*)d_in[25];
    const float* mw4 = (const float*)d_in[26]; const float* mb4 = (const float*)d_in[27];
    const float* mw5 = (const float*)d_in[28]; const float* mb5 = (const float*)d_in[29];

    const int* src = ei;
    const int* dst = ei + N_EDGES;

    float* ws = (float*)d_ws;
    float* stats_e = ws;            // 20 floats
    float* stats_x = ws + 32;       // 32 floats
    float* e_n = ws + 64;                       // 100000*10 = 1,000,000
    float* x_n = ws + 64 + 1000000;             // 20000*16  =   320,000
    float* x1  = ws + 64 + 1000000 + 320000;    // 20000*32  =   640,000
    float* x2  = ws + 64 + 1000000 + 320000 + 640000;  // 20000*64 = 1,280,000
    float* out = (float*)d_out;

    // zero the stats accumulators (ws is poisoned with 0xAA before every call)
    hipMemsetAsync(d_ws, 0, 256, stream);

    stats_kernel<10><<<200, 256, 0, stream>>>(e, N_EDGES, stats_e);
    stats_kernel<16><<<100, 256, 0, stream>>>(x, N_NODES, stats_x);

    normalize_kernel<10><<<(N_EDGES * 10 + 255) / 256, 256, 0, stream>>>(
        e, N_EDGES, stats_e, bn_edge_g, bn_edge_b, e_n);
    normalize_kernel<16><<<(N_NODES * 16 + 255) / 256, 256, 0, stream>>>(
        x, N_NODES, stats_x, bn_node_g, bn_node_b, x_n);

    // layer 1: x1 = x_n @ l1_root + l1_bias, then scatter-add messages
    root_kernel<16, 32><<<(N_NODES + 255) / 256, 256, 0, stream>>>(x_n, N_NODES, l1_root, l1_bias, x1);
    conv_edge_kernel<16, 32, 16, 8><<<(N_EDGES + 255) / 256, 256, 0, stream>>>(
        e_n, src, dst, x_n, nn1_w1, nn1_b1, nn1_w2, nn1_b2, x1, N_EDGES);

    // layer 2
    root_kernel<32, 64><<<(N_NODES + 255) / 256, 256, 0, stream>>>(x1, N_NODES, l2_root, l2_bias, x2);
    conv_edge_kernel<32, 64, 32, 8><<<(N_EDGES + 255) / 256, 256, 0, stream>>>(
        e_n, src, dst, x1, nn2_w1, nn2_b1, nn2_w2, nn2_b2, x2, N_EDGES);

    // edge MLP
    mlp_kernel<<<(N_EDGES + 255) / 256, 256, 0, stream>>>(
        x2, e_n, src, dst, mw1, mb1, mw2, mb2, mw3, mb3, mw4, mb4, mw5, mb5, out, N_EDGES);
}